// Round 6
// baseline (5687.670 us; speedup 1.0000x reference)
//
#include <hip/hip_runtime.h>
#include <hip/hip_bf16.h>

#define Bn 64
#define Tn 1024
#define In 64
#define Dn 256

typedef short bf16x8 __attribute__((ext_vector_type(8)));
typedef unsigned short u16x8 __attribute__((ext_vector_type(8)));
typedef unsigned short u16x4 __attribute__((ext_vector_type(4)));
typedef float f32x4 __attribute__((ext_vector_type(4)));
typedef unsigned int u32x4 __attribute__((ext_vector_type(4)));

__device__ __forceinline__ unsigned short f2bf(float f){
  unsigned u = __float_as_uint(f);
  u += 0x7fffu + ((u >> 16) & 1u);       // RNE
  return (unsigned short)(u >> 16);
}
__device__ __forceinline__ float sig_(float x){ return 1.f / (1.f + __expf(-x)); }
__device__ __forceinline__ float tanh_(float x){ float e = __expf(2.f * x); return 1.f - 2.f / (e + 1.f); }

__device__ __forceinline__ bf16x8 pack8(const float* f){
  bf16x8 r;
  #pragma unroll
  for (int i = 0; i < 8; ++i) r[i] = (short)f2bf(f[i]);
  return r;
}

// x fp32 -> bf16 precast (removes per-step repack + halves x footprint)
__global__ __launch_bounds__(256) void xcast_kernel(
    const float* __restrict__ x, unsigned short* __restrict__ xbf)
{
  const int i = (blockIdx.x * 256 + threadIdx.x) * 8;
  const float4 a = *(const float4*)&x[i];
  const float4 b = *(const float4*)&x[i + 4];
  u16x8 o = { f2bf(a.x), f2bf(a.y), f2bf(a.z), f2bf(a.w),
              f2bf(b.x), f2bf(b.y), f2bf(b.z), f2bf(b.w) };
  *(u16x8*)&xbf[i] = o;
}

// 16B system-scope load (bypass L1/L2, read coherence point), imm offset
#define LDH(reg, OFF) \
  asm volatile("global_load_dwordx4 %0, %1, off offset:" OFF " sc0 sc1" \
               : "=v"(reg) : "v"(hbase) : "memory")

// ---------------------------------------------------------------------------
// LSTM scan v6: v5 structure (16 WGs x 4 waves, reg-resident weight frags)
// with a single-RTT self-validating h exchange:
//  - h stored as fp32 whose low 16 bits carry the step tag (t+1); high 16
//    bits are the RNE bf16 of h, so MFMA inputs are bit-identical to v5.
//  - producer: 2x8B relaxed agent atomic stores, fire-and-forget (no vmcnt
//    ack, no tag array, no ordering).
//  - consumer: polls by LOADING the data (16x dwordx4 sc0 sc1); checks the
//    tag in each 8B granule; retries until all fresh. Poll == data load.
//  - overwrite safety: producer writes h(t) over h(t-2) only after its own
//    h(t-1) loads returned (dataflow), which implies all consumers of
//    h(t-2) in its chain completed. Tags strictly increase -> no ABA.
// ---------------------------------------------------------------------------
__global__ __launch_bounds__(256, 1) void lstm_scan_kernel(
    const unsigned short* __restrict__ xbf, const float* __restrict__ Wih,
    const float* __restrict__ Whh, const float* __restrict__ bih,
    const float* __restrict__ bhh, unsigned short* __restrict__ Hbf,
    float* __restrict__ hxf)
{
  const int w = blockIdx.x;        // dim block 0..15
  const int tid = threadIdx.x;
  const int v = tid >> 6;          // wave 0..3 -> chain v, batches v*16..+16
  const int l = tid & 63;
  const int lr = l & 15, lg = l >> 4;

  // --- W fragments (A operand), bf16, register-resident (160 VGPR) ---
  bf16x8 wfr[4][10];
  {
    const int gate = lr & 3, dimx = lr >> 2;
    #pragma unroll
    for (int mt = 0; mt < 4; ++mt){
      const int dim = w * 16 + dimx * 4 + mt;
      const int row = gate * Dn + dim;
      #pragma unroll
      for (int kt = 0; kt < 8; ++kt){
        float tmp[8];
        *(float4*)&tmp[0] = *(const float4*)&Whh[row * Dn + kt * 32 + lg * 8];
        *(float4*)&tmp[4] = *(const float4*)&Whh[row * Dn + kt * 32 + lg * 8 + 4];
        wfr[mt][kt] = pack8(tmp);
      }
      #pragma unroll
      for (int xt = 0; xt < 2; ++xt){
        float tmp[8];
        *(float4*)&tmp[0] = *(const float4*)&Wih[row * In + xt * 32 + lg * 8];
        *(float4*)&tmp[4] = *(const float4*)&Wih[row * In + xt * 32 + lg * 8 + 4];
        wfr[mt][8 + xt] = pack8(tmp);
      }
    }
  }

  // bias in LDS (keeps 16 VGPRs free): biasL[lg][mt][gate]
  __shared__ float biasL[4][4][4];
  if (tid < 16){
    const int blg = tid >> 2, bmt = tid & 3;
    const int dim = w * 16 + blg * 4 + bmt;
    #pragma unroll
    for (int g = 0; g < 4; ++g)
      biasL[blg][bmt][g] = bih[g * Dn + dim] + bhh[g * Dn + dim];
  }
  __syncthreads();

  float cst[4] = {0.f, 0.f, 0.f, 0.f};
  const int b = v * 16 + lr;               // lane's batch
  const int dim0 = w * 16 + lg * 4;        // lane's first output dim

  // exchange-buffer byte bases (parity 0 / 1)
  const unsigned long long cb0 = (unsigned long long)(uintptr_t)hxf + (unsigned)(b * 1024 + lg * 32);
  const unsigned long long cb1 = cb0 + 65536ull;
  char* const sb0 = (char*)hxf + (b * 1024 + dim0 * 4);

  // x double-buffer, bf16 pre-packed (8+8 VGPR)
  bf16x8 xb0, xb1, xn0, xn1;
  {
    const unsigned short* xr = xbf + (size_t)(b * Tn) * In;
    xb0 = *(const bf16x8*)&xr[lg * 8];
    xb1 = *(const bf16x8*)&xr[32 + lg * 8];
    xn0 = *(const bf16x8*)&xr[In + lg * 8];
    xn1 = *(const bf16x8*)&xr[In + 32 + lg * 8];
  }

  for (int t = 0; t < Tn; ++t){
    bf16x8 hbf0, hbf1, hbf2, hbf3, hbf4, hbf5, hbf6, hbf7;
    if (t > 0){
      const unsigned want = (unsigned)t;                 // tag of h(t-1)
      const unsigned long long hbase = (t & 1) ? cb0 : cb1;   // parity (t-1)&1
      u32x4 A0,A1,A2,A3,A4,A5,A6,A7,A8,A9,A10,A11,A12,A13,A14,A15;
      int ok;
      do {
        LDH(A0,"0");    LDH(A1,"16");   LDH(A2,"128");  LDH(A3,"144");
        LDH(A4,"256");  LDH(A5,"272");  LDH(A6,"384");  LDH(A7,"400");
        LDH(A8,"512");  LDH(A9,"528");  LDH(A10,"640"); LDH(A11,"656");
        LDH(A12,"768"); LDH(A13,"784"); LDH(A14,"896"); LDH(A15,"912");
        // oldest 8 (kt 0..3) complete; thread values through the wait
        asm volatile("s_waitcnt vmcnt(8)"
          : "+v"(A0),"+v"(A1),"+v"(A2),"+v"(A3),"+v"(A4),"+v"(A5),"+v"(A6),"+v"(A7)
          :: "memory");
        __builtin_amdgcn_sched_barrier(0);
        unsigned d;
        d  = ((A0.x ^ want) | (A0.z ^ want)) & 0xFFFFu;
        d |= ((A1.x ^ want) | (A1.z ^ want)) & 0xFFFFu;
        d |= ((A2.x ^ want) | (A2.z ^ want)) & 0xFFFFu;
        d |= ((A3.x ^ want) | (A3.z ^ want)) & 0xFFFFu;
        d |= ((A4.x ^ want) | (A4.z ^ want)) & 0xFFFFu;
        d |= ((A5.x ^ want) | (A5.z ^ want)) & 0xFFFFu;
        d |= ((A6.x ^ want) | (A6.z ^ want)) & 0xFFFFu;
        d |= ((A7.x ^ want) | (A7.z ^ want)) & 0xFFFFu;
        // pack lo: high 16 bits of each fp32 word = RNE bf16 of h
        {
          u32x4 p;
          p = (u32x4){ __builtin_amdgcn_perm(A0.y,A0.x,0x07060302), __builtin_amdgcn_perm(A0.w,A0.z,0x07060302),
                       __builtin_amdgcn_perm(A1.y,A1.x,0x07060302), __builtin_amdgcn_perm(A1.w,A1.z,0x07060302) };
          hbf0 = *(bf16x8*)&p;
          p = (u32x4){ __builtin_amdgcn_perm(A2.y,A2.x,0x07060302), __builtin_amdgcn_perm(A2.w,A2.z,0x07060302),
                       __builtin_amdgcn_perm(A3.y,A3.x,0x07060302), __builtin_amdgcn_perm(A3.w,A3.z,0x07060302) };
          hbf1 = *(bf16x8*)&p;
          p = (u32x4){ __builtin_amdgcn_perm(A4.y,A4.x,0x07060302), __builtin_amdgcn_perm(A4.w,A4.z,0x07060302),
                       __builtin_amdgcn_perm(A5.y,A5.x,0x07060302), __builtin_amdgcn_perm(A5.w,A5.z,0x07060302) };
          hbf2 = *(bf16x8*)&p;
          p = (u32x4){ __builtin_amdgcn_perm(A6.y,A6.x,0x07060302), __builtin_amdgcn_perm(A6.w,A6.z,0x07060302),
                       __builtin_amdgcn_perm(A7.y,A7.x,0x07060302), __builtin_amdgcn_perm(A7.w,A7.z,0x07060302) };
          hbf3 = *(bf16x8*)&p;
        }
        asm volatile("s_waitcnt vmcnt(0)"
          : "+v"(A8),"+v"(A9),"+v"(A10),"+v"(A11),"+v"(A12),"+v"(A13),"+v"(A14),"+v"(A15)
          :: "memory");
        __builtin_amdgcn_sched_barrier(0);
        d |= ((A8.x  ^ want) | (A8.z  ^ want)) & 0xFFFFu;
        d |= ((A9.x  ^ want) | (A9.z  ^ want)) & 0xFFFFu;
        d |= ((A10.x ^ want) | (A10.z ^ want)) & 0xFFFFu;
        d |= ((A11.x ^ want) | (A11.z ^ want)) & 0xFFFFu;
        d |= ((A12.x ^ want) | (A12.z ^ want)) & 0xFFFFu;
        d |= ((A13.x ^ want) | (A13.z ^ want)) & 0xFFFFu;
        d |= ((A14.x ^ want) | (A14.z ^ want)) & 0xFFFFu;
        d |= ((A15.x ^ want) | (A15.z ^ want)) & 0xFFFFu;
        {
          u32x4 p;
          p = (u32x4){ __builtin_amdgcn_perm(A8.y,A8.x,0x07060302),   __builtin_amdgcn_perm(A8.w,A8.z,0x07060302),
                       __builtin_amdgcn_perm(A9.y,A9.x,0x07060302),   __builtin_amdgcn_perm(A9.w,A9.z,0x07060302) };
          hbf4 = *(bf16x8*)&p;
          p = (u32x4){ __builtin_amdgcn_perm(A10.y,A10.x,0x07060302), __builtin_amdgcn_perm(A10.w,A10.z,0x07060302),
                       __builtin_amdgcn_perm(A11.y,A11.x,0x07060302), __builtin_amdgcn_perm(A11.w,A11.z,0x07060302) };
          hbf5 = *(bf16x8*)&p;
          p = (u32x4){ __builtin_amdgcn_perm(A12.y,A12.x,0x07060302), __builtin_amdgcn_perm(A12.w,A12.z,0x07060302),
                       __builtin_amdgcn_perm(A13.y,A13.x,0x07060302), __builtin_amdgcn_perm(A13.w,A13.z,0x07060302) };
          hbf6 = *(bf16x8*)&p;
          p = (u32x4){ __builtin_amdgcn_perm(A14.y,A14.x,0x07060302), __builtin_amdgcn_perm(A14.w,A14.z,0x07060302),
                       __builtin_amdgcn_perm(A15.y,A15.x,0x07060302), __builtin_amdgcn_perm(A15.w,A15.z,0x07060302) };
          hbf7 = *(bf16x8*)&p;
        }
        ok = __all((int)(d == 0));
      } while (!ok);
    }

    // acc init: bias (LDS, volatile to stay off the VGPR budget) + x
    f32x4 acc[4];
    #pragma unroll
    for (int mt = 0; mt < 4; ++mt){
      volatile const float* bp = &biasL[lg][mt][0];
      f32x4 a = {bp[0], bp[1], bp[2], bp[3]};
      a = __builtin_amdgcn_mfma_f32_16x16x32_bf16(wfr[mt][8], xb0, a, 0, 0, 0);
      a = __builtin_amdgcn_mfma_f32_16x16x32_bf16(wfr[mt][9], xb1, a, 0, 0, 0);
      acc[mt] = a;
    }
    if (t > 0){
      #pragma unroll
      for (int mt = 0; mt < 4; ++mt){
        acc[mt] = __builtin_amdgcn_mfma_f32_16x16x32_bf16(wfr[mt][0], hbf0, acc[mt], 0, 0, 0);
        acc[mt] = __builtin_amdgcn_mfma_f32_16x16x32_bf16(wfr[mt][1], hbf1, acc[mt], 0, 0, 0);
        acc[mt] = __builtin_amdgcn_mfma_f32_16x16x32_bf16(wfr[mt][2], hbf2, acc[mt], 0, 0, 0);
        acc[mt] = __builtin_amdgcn_mfma_f32_16x16x32_bf16(wfr[mt][3], hbf3, acc[mt], 0, 0, 0);
        acc[mt] = __builtin_amdgcn_mfma_f32_16x16x32_bf16(wfr[mt][4], hbf4, acc[mt], 0, 0, 0);
        acc[mt] = __builtin_amdgcn_mfma_f32_16x16x32_bf16(wfr[mt][5], hbf5, acc[mt], 0, 0, 0);
        acc[mt] = __builtin_amdgcn_mfma_f32_16x16x32_bf16(wfr[mt][6], hbf6, acc[mt], 0, 0, 0);
        acc[mt] = __builtin_amdgcn_mfma_f32_16x16x32_bf16(wfr[mt][7], hbf7, acc[mt], 0, 0, 0);
      }
    }

    // elementwise; build tagged fp32 words (hi16 = RNE bf16, lo16 = t+1)
    const unsigned tag2 = (unsigned)(t + 1);
    unsigned wd[4];
    unsigned long long hq = 0;
    #pragma unroll
    for (int mt = 0; mt < 4; ++mt){
      const float ig = sig_(acc[mt][0]);
      const float fg = sig_(acc[mt][1]);
      const float gg = tanh_(acc[mt][2]);
      const float og = sig_(acc[mt][3]);
      const float c = fg * cst[mt] + ig * gg;
      cst[mt] = c;
      const float h = og * tanh_(c);
      unsigned u = __float_as_uint(h);
      u = (u + 0x7fffu + ((u >> 16) & 1u)) & 0xFFFF0000u;   // RNE bf16 in hi16
      wd[mt] = u | tag2;
      hq |= (unsigned long long)(u >> 16) << (16 * mt);
    }
    // fire-and-forget publish: 2x8B agent atomics (no ack, no tag store)
    {
      unsigned long long* hp =
          (unsigned long long*)(sb0 + ((t & 1) ? 65536 : 0));
      const unsigned long long q0 = (unsigned long long)wd[0] | ((unsigned long long)wd[1] << 32);
      const unsigned long long q1 = (unsigned long long)wd[2] | ((unsigned long long)wd[3] << 32);
      __hip_atomic_store(&hp[0], q0, __ATOMIC_RELAXED, __HIP_MEMORY_SCOPE_AGENT);
      __hip_atomic_store(&hp[1], q1, __ATOMIC_RELAXED, __HIP_MEMORY_SCOPE_AGENT);
    }
    // history copy for attn/mlp (plain cached store, off critical path)
    *(unsigned long long*)&Hbf[(size_t)(b * Tn + t) * Dn + dim0] = hq;

    // rotate x and prefetch x(t+2)
    xb0 = xn0; xb1 = xn1;
    {
      const int tn = (t + 2 < Tn) ? t + 2 : Tn - 1;
      const unsigned short* xr = xbf + (size_t)(b * Tn + tn) * In;
      xn0 = *(const bf16x8*)&xr[lg * 8];
      xn1 = *(const bf16x8*)&xr[32 + lg * 8];
    }
  }
}

// ---------------------------------------------------------------------------
// Flash attention, Q=K=V=H (bf16), unscaled, causal. One WG per (b, 64-row qtile).
// ---------------------------------------------------------------------------
__global__ __launch_bounds__(256, 1) void attn_kernel(
    const unsigned short* __restrict__ Hbf, unsigned short* __restrict__ ctxbf)
{
  const int bid = blockIdx.x;
  const int b = bid >> 4, qt = bid & 15;
  const int q0 = qt * 64;
  const int tid = threadIdx.x;
  const int w = tid >> 6, l = tid & 63;
  const int lr = l & 15, lg = l >> 4;

  __shared__ unsigned short Qs[64 * 256];
  __shared__ unsigned short Ks[64 * 256];
  __shared__ unsigned short Vt[256 * 64];   // transposed: [d][s]
  __shared__ unsigned short Ps[64 * 64];

  {
    const int r = tid >> 2, cs = (tid & 3) * 64;
    #pragma unroll
    for (int jj = 0; jj < 8; ++jj){
      const int c = cs + jj * 8;
      u16x8 v = *(const u16x8*)&Hbf[(b * Tn + q0 + r) * Dn + c];
      *(u16x8*)((char*)Qs + (((r * 256 + c) * 2) ^ ((r & 7) << 4))) = v;
    }
  }
  __syncthreads();
  bf16x8 qf[8];
  #pragma unroll
  for (int kc = 0; kc < 8; ++kc){
    const int r = w * 16 + lr, c = kc * 32 + lg * 8;
    qf[kc] = *(const bf16x8*)((const char*)Qs + (((r * 256 + c) * 2) ^ ((r & 7) << 4)));
  }

  float m_i[4], l_i[4];
  f32x4 o_acc[16];
  #pragma unroll
  for (int i = 0; i < 4; ++i){ m_i[i] = -__builtin_inff(); l_i[i] = 0.f; }
  #pragma unroll
  for (int n = 0; n < 16; ++n) o_acc[n] = (f32x4){0.f, 0.f, 0.f, 0.f};

  for (int kt = 0; kt <= qt; ++kt){
    const int s0 = kt * 64;
    __syncthreads();    // previous-iteration K/Vt consumers done
    {
      const int r = tid >> 2, cs = (tid & 3) * 64;
      #pragma unroll
      for (int jj = 0; jj < 8; ++jj){
        const int c = cs + jj * 8;
        u16x8 v = *(const u16x8*)&Hbf[(b * Tn + s0 + r) * Dn + c];
        *(u16x8*)((char*)Ks + (((r * 256 + c) * 2) ^ ((r & 7) << 4))) = v;
      }
    }
    {
      const int s = tid & 63, db = tid >> 6;
      #pragma unroll
      for (int jj = 0; jj < 8; ++jj){
        const int d0 = db * 64 + jj * 8;
        u16x8 v = *(const u16x8*)&Hbf[(b * Tn + s0 + s) * Dn + d0];
        #pragma unroll
        for (int e = 0; e < 8; ++e){
          const int d = d0 + e;
          *(unsigned short*)((char*)Vt + (((d * 64 + s) * 2) ^ ((d & 7) << 4))) = (unsigned short)v[e];
        }
      }
    }
    __syncthreads();
    f32x4 sacc[4];
    #pragma unroll
    for (int n = 0; n < 4; ++n) sacc[n] = (f32x4){0.f, 0.f, 0.f, 0.f};
    #pragma unroll
    for (int kc = 0; kc < 8; ++kc){
      #pragma unroll
      for (int n = 0; n < 4; ++n){
        const int r = n * 16 + lr, c = kc * 32 + lg * 8;
        bf16x8 kfr = *(const bf16x8*)((const char*)Ks + (((r * 256 + c) * 2) ^ ((r & 7) << 4)));
        sacc[n] = __builtin_amdgcn_mfma_f32_16x16x32_bf16(qf[kc], kfr, sacc[n], 0, 0, 0);
      }
    }
    if (kt == qt){
      #pragma unroll
      for (int n = 0; n < 4; ++n)
        #pragma unroll
        for (int i = 0; i < 4; ++i){
          const int scol = s0 + n * 16 + lr;
          const int qrow = q0 + w * 16 + lg * 4 + i;
          if (scol > qrow) sacc[n][i] = -__builtin_inff();
        }
    }
    float rmax[4], alpha[4], rsum[4];
    #pragma unroll
    for (int i = 0; i < 4; ++i){
      float vv = fmaxf(fmaxf(sacc[0][i], sacc[1][i]), fmaxf(sacc[2][i], sacc[3][i]));
      vv = fmaxf(vv, __shfl_xor(vv, 1));
      vv = fmaxf(vv, __shfl_xor(vv, 2));
      vv = fmaxf(vv, __shfl_xor(vv, 4));
      vv = fmaxf(vv, __shfl_xor(vv, 8));
      rmax[i] = vv;
    }
    #pragma unroll
    for (int i = 0; i < 4; ++i){
      const float mn = fmaxf(m_i[i], rmax[i]);
      alpha[i] = __expf(m_i[i] - mn);
      m_i[i] = mn;
      rsum[i] = 0.f;
    }
    #pragma unroll
    for (int n = 0; n < 4; ++n){
      #pragma unroll
      for (int i = 0; i < 4; ++i){
        const float pv = __expf(sacc[n][i] - m_i[i]);
        rsum[i] += pv;
        const int r = w * 16 + lg * 4 + i, c = n * 16 + lr;
        *(unsigned short*)((char*)Ps + (((r * 64 + c) * 2) ^ ((r & 7) << 4))) = f2bf(pv);
      }
    }
    #pragma unroll
    for (int i = 0; i < 4; ++i){
      float vv = rsum[i];
      vv += __shfl_xor(vv, 1);
      vv += __shfl_xor(vv, 2);
      vv += __shfl_xor(vv, 4);
      vv += __shfl_xor(vv, 8);
      l_i[i] = l_i[i] * alpha[i] + vv;
    }
    #pragma unroll
    for (int n = 0; n < 16; ++n)
      #pragma unroll
      for (int i = 0; i < 4; ++i) o_acc[n][i] *= alpha[i];
    #pragma unroll
    for (int kc = 0; kc < 2; ++kc){
      const int r = w * 16 + lr, c = kc * 32 + lg * 8;
      bf16x8 pfr = *(const bf16x8*)((const char*)Ps + (((r * 64 + c) * 2) ^ ((r & 7) << 4)));
      #pragma unroll
      for (int n = 0; n < 16; ++n){
        const int vr = n * 16 + lr, vc = kc * 32 + lg * 8;
        bf16x8 vfr = *(const bf16x8*)((const char*)Vt + (((vr * 64 + vc) * 2) ^ ((vr & 7) << 4)));
        o_acc[n] = __builtin_amdgcn_mfma_f32_16x16x32_bf16(pfr, vfr, o_acc[n], 0, 0, 0);
      }
    }
  }
  #pragma unroll
  for (int n = 0; n < 16; ++n)
    #pragma unroll
    for (int i = 0; i < 4; ++i){
      const float vv = o_acc[n][i] / l_i[i];
      const int q = q0 + w * 16 + lg * 4 + i;
      const int d = n * 16 + lr;
      ctxbf[(b * Tn + q) * Dn + d] = f2bf(vv);
    }
}

// ---------------------------------------------------------------------------
// MLP: out = relu([H|ctx] @ W1^T + b1) @ W2^T + b2, fused per 64-row M tile.
// ---------------------------------------------------------------------------
__global__ __launch_bounds__(256, 1) void mlp_kernel(
    const unsigned short* __restrict__ Hbf, const unsigned short* __restrict__ ctxbf,
    const float* __restrict__ W1, const float* __restrict__ b1,
    const float* __restrict__ W2, const float* __restrict__ b2,
    float* __restrict__ out)
{
  const int m0 = blockIdx.x * 64;
  const int tid = threadIdx.x;
  const int w = tid >> 6, l = tid & 63;
  const int lr = l & 15, lg = l >> 4;

  __shared__ unsigned short As[64 * 512];
  __shared__ unsigned short Ws[64 * 512];

  {
    const int r = tid >> 2, cs = (tid & 3) * 128;
    #pragma unroll
    for (int jj = 0; jj < 16; ++jj){
      const int c = cs + jj * 8;
      u16x8 v;
      if (c < 256) v = *(const u16x8*)&Hbf[(m0 + r) * Dn + c];
      else         v = *(const u16x8*)&ctxbf[(m0 + r) * Dn + (c - 256)];
      *(u16x8*)((char*)As + (((r * 512 + c) * 2) ^ ((r & 7) << 4))) = v;
    }
  }
  f32x4 hacc[16];
  #pragma unroll
  for (int n = 0; n < 16; ++n) hacc[n] = (f32x4){0.f, 0.f, 0.f, 0.f};

  for (int nb = 0; nb < 4; ++nb){
    __syncthreads();
    {
      const int r = tid >> 2, cs = (tid & 3) * 128;
      #pragma unroll
      for (int jj = 0; jj < 32; ++jj){
        const int c = cs + jj * 4;
        const float4 v = *(const float4*)&W1[(nb * 64 + r) * 512 + c];
        u16x4 pk = { f2bf(v.x), f2bf(v.y), f2bf(v.z), f2bf(v.w) };
        *(u16x4*)((char*)Ws + (((r * 512 + c) * 2) ^ ((r & 7) << 4))) = pk;
      }
    }
    __syncthreads();
    #pragma unroll
    for (int kc = 0; kc < 16; ++kc){
      const int ar = w * 16 + lr, ac = kc * 32 + lg * 8;
      bf16x8 af = *(const bf16x8*)((const char*)As + (((ar * 512 + ac) * 2) ^ ((ar & 7) << 4)));
      #pragma unroll
      for (int n = 0; n < 4; ++n){
        const int br = n * 16 + lr;
        bf16x8 bf = *(const bf16x8*)((const char*)Ws + (((br * 512 + ac) * 2) ^ ((br & 7) << 4)));
        hacc[nb * 4 + n] = __builtin_amdgcn_mfma_f32_16x16x32_bf16(af, bf, hacc[nb * 4 + n], 0, 0, 0);
      }
    }
  }
  __syncthreads();
  #pragma unroll
  for (int nn = 0; nn < 16; ++nn){
    const int col = (nn >> 2) * 64 + (nn & 3) * 16 + lr;
    const float bv = b1[col];
    #pragma unroll
    for (int i = 0; i < 4; ++i){
      float v = hacc[nn][i] + bv;
      v = v > 0.f ? v : 0.f;
      const int r = w * 16 + lg * 4 + i;
      *(unsigned short*)((char*)As + (((r * 256 + col) * 2) ^ ((r & 7) << 4))) = f2bf(v);
    }
  }
  {
    const int r = tid >> 2, cs = (tid & 3) * 64;
    #pragma unroll
    for (int jj = 0; jj < 16; ++jj){
      const int c = cs + jj * 4;
      const float4 v = *(const float4*)&W2[r * 256 + c];
      u16x4 pk = { f2bf(v.x), f2bf(v.y), f2bf(v.z), f2bf(v.w) };
      *(u16x4*)((char*)Ws + (((r * 256 + c) * 2) ^ ((r & 7) << 4))) = pk;
    }
  }
  __syncthreads();
  f32x4 oacc[4];
  #pragma unroll
  for (int n = 0; n < 4; ++n) oacc[n] = (f32x4){0.f, 0.f, 0.f, 0.f};
  #pragma unroll
  for (int kc = 0; kc < 8; ++kc){
    const int ar = w * 16 + lr, ac = kc * 32 + lg * 8;
    bf16x8 af = *(const bf16x8*)((const char*)As + (((ar * 256 + ac) * 2) ^ ((ar & 7) << 4)));
    #pragma unroll
    for (int n = 0; n < 4; ++n){
      const int br = n * 16 + lr;
      bf16x8 bf = *(const bf16x8*)((const char*)Ws + (((br * 256 + ac) * 2) ^ ((br & 7) << 4)));
      oacc[n] = __builtin_amdgcn_mfma_f32_16x16x32_bf16(af, bf, oacc[n], 0, 0, 0);
    }
  }
  #pragma unroll
  for (int n = 0; n < 4; ++n)
    #pragma unroll
    for (int i = 0; i < 4; ++i){
      const int ii = n * 16 + lr;
      const int m = m0 + w * 16 + lg * 4 + i;
      out[m * In + ii] = oacc[n][i] + b2[ii];
    }
}

extern "C" void kernel_launch(void* const* d_in, const int* in_sizes, int n_in,
                              void* d_out, int out_size, void* d_ws, size_t ws_size,
                              hipStream_t stream)
{
  (void)in_sizes; (void)n_in; (void)out_size; (void)ws_size;
  const float* x   = (const float*)d_in[0];
  const float* Wih = (const float*)d_in[1];
  const float* Whh = (const float*)d_in[2];
  const float* bih = (const float*)d_in[3];
  const float* bhh = (const float*)d_in[4];
  const float* W1  = (const float*)d_in[5];
  const float* b1  = (const float*)d_in[6];
  const float* W2  = (const float*)d_in[7];
  const float* b2  = (const float*)d_in[8];
  float* out = (float*)d_out;

  char* ws = (char*)d_ws;
  unsigned short* Hbf   = (unsigned short*)ws;                              // 32 MB
  unsigned short* ctxbf = (unsigned short*)(ws + (size_t)32 * 1024 * 1024); // 32 MB (attn output)
  unsigned short* xbf   = ctxbf;            // 8 MB, reused BEFORE attn writes ctx
  float* hxf = (float*)(ws + (size_t)64 * 1024 * 1024);                     // 128 KB exchange

  // zero exchange buffer: tag 0 never matches any step tag (1..1024),
  // and kills leftover tags from a previous launch.
  hipMemsetAsync(hxf, 0, 2 * 64 * 1024, stream);
  xcast_kernel<<<(Bn * Tn * In) / (256 * 8), 256, 0, stream>>>(x, (unsigned short*)xbf);
  lstm_scan_kernel<<<16, 256, 0, stream>>>(xbf, Wih, Whh, bih, bhh, Hbf, hxf);
  attn_kernel<<<Bn * 16, 256, 0, stream>>>(Hbf, ctxbf);
  mlp_kernel<<<(Bn * Tn) / 64, 256, 0, stream>>>(Hbf, ctxbf, W1, b1, W2, b2, out);
}

// Round 7
// 5039.370 us; speedup vs baseline: 1.1286x; 1.1286x over previous
//
#include <hip/hip_runtime.h>
#include <hip/hip_bf16.h>

#define Bn 64
#define Tn 1024
#define In 64
#define Dn 256

typedef short bf16x8 __attribute__((ext_vector_type(8)));
typedef unsigned short u16x8 __attribute__((ext_vector_type(8)));
typedef unsigned short u16x4 __attribute__((ext_vector_type(4)));
typedef float f32x4 __attribute__((ext_vector_type(4)));
typedef unsigned int u32x2 __attribute__((ext_vector_type(2)));

__device__ __forceinline__ unsigned short f2bf(float f){
  unsigned u = __float_as_uint(f);
  u += 0x7fffu + ((u >> 16) & 1u);       // RNE
  return (unsigned short)(u >> 16);
}
__device__ __forceinline__ float sig_(float x){ return 1.f / (1.f + __expf(-x)); }
__device__ __forceinline__ float tanh_(float x){ float e = __expf(2.f * x); return 1.f - 2.f / (e + 1.f); }

__device__ __forceinline__ bf16x8 pack8(const float* f){
  bf16x8 r;
  #pragma unroll
  for (int i = 0; i < 8; ++i) r[i] = (short)f2bf(f[i]);
  return r;
}

// ---------------------------------------------------------------------------
// gates_x: Gx = x @ Wih^T + bih + bhh, written bf16 in the scan's fragment
// layout: per (chain,t,u): [jmt 8][lane 64][gate 4]. Lane (lg,lr) of slot
// (u,j,mt) holds gates i=0..3 of dim = u*32+j*16+lg*4+mt, batch = chain*16+lr
// (exactly the MFMA C layout the scan produces/consumes). 1024 WGs x 4 t.
// ---------------------------------------------------------------------------
__global__ __launch_bounds__(256, 1) void gates_x_kernel(
    const float* __restrict__ x, const float* __restrict__ Wih,
    const float* __restrict__ bih, const float* __restrict__ bhh,
    unsigned short* __restrict__ Gx)
{
  const int bid = blockIdx.x;
  const int chain = bid >> 8;
  const int t0 = (bid & 255) * 4;
  const int tid = threadIdx.x;
  const int wv = tid >> 6;
  const int l = tid & 63;
  const int lr = l & 15, lg = l >> 4;
  const int gate = lr & 3, dimx = lr >> 2;

  __shared__ float bsum[1024];
  for (int r = tid; r < 1024; r += 256) bsum[r] = bih[r] + bhh[r];
  __syncthreads();

  // A-frags for 16 tiles (u' x j x mt) x kt2, register-resident (128 VGPR)
  bf16x8 wa[16][2];
  #pragma unroll
  for (int up = 0; up < 2; ++up)
    #pragma unroll
    for (int j = 0; j < 2; ++j)
      #pragma unroll
      for (int mt = 0; mt < 4; ++mt){
        const int u = wv * 2 + up;
        const int row = gate * Dn + u * 32 + j * 16 + dimx * 4 + mt;
        #pragma unroll
        for (int kt = 0; kt < 2; ++kt){
          float tmp[8];
          *(float4*)&tmp[0] = *(const float4*)&Wih[row * In + kt * 32 + lg * 8];
          *(float4*)&tmp[4] = *(const float4*)&Wih[row * In + kt * 32 + lg * 8 + 4];
          wa[(up * 2 + j) * 4 + mt][kt] = pack8(tmp);
        }
      }

  const int b = chain * 16 + lr;
  for (int tt = 0; tt < 4; ++tt){
    const int t = t0 + tt;
    bf16x8 xb[2];
    #pragma unroll
    for (int kt = 0; kt < 2; ++kt){
      float tmp[8];
      *(float4*)&tmp[0] = *(const float4*)&x[(size_t)(b * Tn + t) * In + kt * 32 + lg * 8];
      *(float4*)&tmp[4] = *(const float4*)&x[(size_t)(b * Tn + t) * In + kt * 32 + lg * 8 + 4];
      xb[kt] = pack8(tmp);
    }
    #pragma unroll
    for (int up = 0; up < 2; ++up)
      #pragma unroll
      for (int j = 0; j < 2; ++j)
        #pragma unroll
        for (int mt = 0; mt < 4; ++mt){
          const int u = wv * 2 + up;
          f32x4 a = {0.f, 0.f, 0.f, 0.f};
          a = __builtin_amdgcn_mfma_f32_16x16x32_bf16(wa[(up*2+j)*4+mt][0], xb[0], a, 0, 0, 0);
          a = __builtin_amdgcn_mfma_f32_16x16x32_bf16(wa[(up*2+j)*4+mt][1], xb[1], a, 0, 0, 0);
          const int dim = u * 32 + j * 16 + lg * 4 + mt;
          u16x4 o;
          #pragma unroll
          for (int i = 0; i < 4; ++i) o[i] = f2bf(a[i] + bsum[i * Dn + dim]);
          const size_t off = (((size_t)(chain * Tn + t) * 8 + u) * 8 + (j * 4 + mt)) * 256
                             + (lg * 16 + lr) * 4;
          *(u16x4*)&Gx[off] = o;
        }
  }
}

// ---------------------------------------------------------------------------
// LSTM scan v7: 4 WGs (one per 16-batch chain) x 512 threads (8 waves).
// Wave u owns dims [u*32, u*32+32) x 4 gates. Whh bf16 fragments:
//   regs  (46 units): j0 all mt/kt (32) + j1mt0 kt0..7 (8) + j1mt3 kt2..7 (6)
//   LDS   (18 units): j1mt1 kt0..7, j1mt2 kt0..7, j1mt3 kt0..1  (144 KB)
// h broadcast via 8 KB LDS [db 32][batch 16][8 dims] (16 B frags, 2-way-free).
// K=256 (x-path precomputed in Gx, prefetched 1 step ahead). Zero inter-WG
// communication; 2 __syncthreads per step.
// ---------------------------------------------------------------------------
__global__ __launch_bounds__(512, 1) void lstm_scan_kernel(
    const unsigned short* __restrict__ Gx, const float* __restrict__ Whh,
    unsigned short* __restrict__ Hbf)
{
  const int chain = blockIdx.x;
  const int tid = threadIdx.x;
  const int u = tid >> 6;
  const int l = tid & 63;
  const int lr = l & 15, lg = l >> 4;
  const int gate = lr & 3, dimx = lr >> 2;

  __shared__ unsigned short WL[8][18 * 512];   // 144 KB
  __shared__ unsigned short hL[32][16][8];     // 8 KB

  // ---- register weight fragments ----
  bf16x8 w0[4][8], w1m0[8], w1m3h[6];
  #pragma unroll
  for (int mt = 0; mt < 4; ++mt){
    const int row = gate * Dn + u * 32 + dimx * 4 + mt;          // j=0
    #pragma unroll
    for (int kt = 0; kt < 8; ++kt){
      float tmp[8];
      *(float4*)&tmp[0] = *(const float4*)&Whh[row * Dn + kt * 32 + lg * 8];
      *(float4*)&tmp[4] = *(const float4*)&Whh[row * Dn + kt * 32 + lg * 8 + 4];
      w0[mt][kt] = pack8(tmp);
    }
  }
  {
    const int row = gate * Dn + u * 32 + 16 + dimx * 4 + 0;      // j=1, mt=0
    #pragma unroll
    for (int kt = 0; kt < 8; ++kt){
      float tmp[8];
      *(float4*)&tmp[0] = *(const float4*)&Whh[row * Dn + kt * 32 + lg * 8];
      *(float4*)&tmp[4] = *(const float4*)&Whh[row * Dn + kt * 32 + lg * 8 + 4];
      w1m0[kt] = pack8(tmp);
    }
  }
  {
    const int row = gate * Dn + u * 32 + 16 + dimx * 4 + 3;      // j=1, mt=3, kt2..7
    #pragma unroll
    for (int kt = 2; kt < 8; ++kt){
      float tmp[8];
      *(float4*)&tmp[0] = *(const float4*)&Whh[row * Dn + kt * 32 + lg * 8];
      *(float4*)&tmp[4] = *(const float4*)&Whh[row * Dn + kt * 32 + lg * 8 + 4];
      w1m3h[kt - 2] = pack8(tmp);
    }
  }
  // ---- LDS weight staging: lane writes its own future A-frags ----
  // units 0..7 = (j1,mt1,kt), 8..15 = (j1,mt2,kt), 16..17 = (j1,mt3,kt0..1)
  #pragma unroll
  for (int mt = 1; mt < 3; ++mt){
    const int row = gate * Dn + u * 32 + 16 + dimx * 4 + mt;
    #pragma unroll
    for (int kt = 0; kt < 8; ++kt){
      float tmp[8];
      *(float4*)&tmp[0] = *(const float4*)&Whh[row * Dn + kt * 32 + lg * 8];
      *(float4*)&tmp[4] = *(const float4*)&Whh[row * Dn + kt * 32 + lg * 8 + 4];
      *(bf16x8*)&WL[u][((mt - 1) * 8 + kt) * 512 + lg * 128 + lr * 8] = pack8(tmp);
    }
  }
  {
    const int row = gate * Dn + u * 32 + 16 + dimx * 4 + 3;
    #pragma unroll
    for (int kt = 0; kt < 2; ++kt){
      float tmp[8];
      *(float4*)&tmp[0] = *(const float4*)&Whh[row * Dn + kt * 32 + lg * 8];
      *(float4*)&tmp[4] = *(const float4*)&Whh[row * Dn + kt * 32 + lg * 8 + 4];
      *(bf16x8*)&WL[u][(16 + kt) * 512 + lg * 128 + lr * 8] = pack8(tmp);
    }
  }
  // hL zero (h(-1) = 0)
  for (int i = tid; i < 32 * 16 * 8; i += 512) ((unsigned short*)hL)[i] = 0;
  __syncthreads();

  float cst[8] = {0.f, 0.f, 0.f, 0.f, 0.f, 0.f, 0.f, 0.f};
  const int lane64 = lg * 16 + lr;

  // Gx prefetch (t=0)
  u32x2 g[8];
  {
    const unsigned short* gxp = Gx + ((size_t)(chain * Tn + 0) * 8 + u) * 2048;
    #pragma unroll
    for (int jm = 0; jm < 8; ++jm)
      g[jm] = *(const u32x2*)&gxp[jm * 256 + lane64 * 4];
  }

  const size_t hbB = (size_t)(chain * 16 + lr) * Tn * Dn;

  for (int t = 0; t < Tn; ++t){
    f32x4 acc[8];
    #pragma unroll
    for (int i = 0; i < 8; ++i) acc[i] = (f32x4){0.f, 0.f, 0.f, 0.f};

    #pragma unroll
    for (int kt = 0; kt < 8; ++kt){
      const bf16x8 hf = *(const bf16x8*)&hL[kt * 4 + lg][lr][0];
      acc[0] = __builtin_amdgcn_mfma_f32_16x16x32_bf16(w0[0][kt], hf, acc[0], 0, 0, 0);
      acc[1] = __builtin_amdgcn_mfma_f32_16x16x32_bf16(w0[1][kt], hf, acc[1], 0, 0, 0);
      acc[2] = __builtin_amdgcn_mfma_f32_16x16x32_bf16(w0[2][kt], hf, acc[2], 0, 0, 0);
      acc[3] = __builtin_amdgcn_mfma_f32_16x16x32_bf16(w0[3][kt], hf, acc[3], 0, 0, 0);
      acc[4] = __builtin_amdgcn_mfma_f32_16x16x32_bf16(w1m0[kt], hf, acc[4], 0, 0, 0);
      acc[5] = __builtin_amdgcn_mfma_f32_16x16x32_bf16(
                 *(const bf16x8*)&WL[u][(0 * 8 + kt) * 512 + lg * 128 + lr * 8], hf, acc[5], 0, 0, 0);
      acc[6] = __builtin_amdgcn_mfma_f32_16x16x32_bf16(
                 *(const bf16x8*)&WL[u][(1 * 8 + kt) * 512 + lg * 128 + lr * 8], hf, acc[6], 0, 0, 0);
      bf16x8 a7;
      if (kt < 2) a7 = *(const bf16x8*)&WL[u][(16 + kt) * 512 + lg * 128 + lr * 8];
      else        a7 = w1m3h[kt - 2];
      acc[7] = __builtin_amdgcn_mfma_f32_16x16x32_bf16(a7, hf, acc[7], 0, 0, 0);
    }
    __syncthreads();                         // B1: all hL(t-1) reads consumed

    // elementwise: lane holds 4 gates of dim (u*32 + j*16 + lg*4 + mt), batch lr
    unsigned long long hq0 = 0, hq1 = 0;
    #pragma unroll
    for (int jm = 0; jm < 8; ++jm){
      const int mt = jm & 3;
      const unsigned glo = g[jm][0], ghi = g[jm][1];
      const float gi = __uint_as_float(glo << 16)         + acc[jm][0];
      const float gf = __uint_as_float(glo & 0xFFFF0000u) + acc[jm][1];
      const float gg = __uint_as_float(ghi << 16)         + acc[jm][2];
      const float go = __uint_as_float(ghi & 0xFFFF0000u) + acc[jm][3];
      const float ig = sig_(gi), fg = sig_(gf), gv = tanh_(gg), og = sig_(go);
      const float c = fg * cst[jm] + ig * gv;
      cst[jm] = c;
      const float h = og * tanh_(c);
      const unsigned long long hb = (unsigned long long)f2bf(h) << (16 * mt);
      if (jm < 4) hq0 |= hb; else hq1 |= hb;
    }
    // publish h(t) to LDS (consumed next step by all waves)
    {
      const int db0 = u * 4 + (lg >> 1);
      *(unsigned long long*)&hL[db0][lr][(lg & 1) * 4]     = hq0;   // j=0 dims
      *(unsigned long long*)&hL[db0 + 2][lr][(lg & 1) * 4] = hq1;   // j=1 dims
    }
    // history for attn/mlp
    {
      const size_t o = hbB + (size_t)t * Dn + u * 32 + lg * 4;
      *(unsigned long long*)&Hbf[o]      = hq0;
      *(unsigned long long*)&Hbf[o + 16] = hq1;
    }
    // Gx prefetch t+1
    {
      const int tn = (t + 1 < Tn) ? t + 1 : t;
      const unsigned short* gxp = Gx + ((size_t)(chain * Tn + tn) * 8 + u) * 2048;
      #pragma unroll
      for (int jm = 0; jm < 8; ++jm)
        g[jm] = *(const u32x2*)&gxp[jm * 256 + lane64 * 4];
    }
    __syncthreads();                         // B2: hL(t) visible to all waves
  }
}

// ---------------------------------------------------------------------------
// Flash attention, Q=K=V=H (bf16), unscaled, causal. One WG per (b, 64-row qtile).
// ---------------------------------------------------------------------------
__global__ __launch_bounds__(256, 1) void attn_kernel(
    const unsigned short* __restrict__ Hbf, unsigned short* __restrict__ ctxbf)
{
  const int bid = blockIdx.x;
  const int b = bid >> 4, qt = bid & 15;
  const int q0 = qt * 64;
  const int tid = threadIdx.x;
  const int w = tid >> 6, l = tid & 63;
  const int lr = l & 15, lg = l >> 4;

  __shared__ unsigned short Qs[64 * 256];
  __shared__ unsigned short Ks[64 * 256];
  __shared__ unsigned short Vt[256 * 64];   // transposed: [d][s]
  __shared__ unsigned short Ps[64 * 64];

  {
    const int r = tid >> 2, cs = (tid & 3) * 64;
    #pragma unroll
    for (int jj = 0; jj < 8; ++jj){
      const int c = cs + jj * 8;
      u16x8 v = *(const u16x8*)&Hbf[(b * Tn + q0 + r) * Dn + c];
      *(u16x8*)((char*)Qs + (((r * 256 + c) * 2) ^ ((r & 7) << 4))) = v;
    }
  }
  __syncthreads();
  bf16x8 qf[8];
  #pragma unroll
  for (int kc = 0; kc < 8; ++kc){
    const int r = w * 16 + lr, c = kc * 32 + lg * 8;
    qf[kc] = *(const bf16x8*)((const char*)Qs + (((r * 256 + c) * 2) ^ ((r & 7) << 4)));
  }

  float m_i[4], l_i[4];
  f32x4 o_acc[16];
  #pragma unroll
  for (int i = 0; i < 4; ++i){ m_i[i] = -__builtin_inff(); l_i[i] = 0.f; }
  #pragma unroll
  for (int n = 0; n < 16; ++n) o_acc[n] = (f32x4){0.f, 0.f, 0.f, 0.f};

  for (int kt = 0; kt <= qt; ++kt){
    const int s0 = kt * 64;
    __syncthreads();
    {
      const int r = tid >> 2, cs = (tid & 3) * 64;
      #pragma unroll
      for (int jj = 0; jj < 8; ++jj){
        const int c = cs + jj * 8;
        u16x8 v = *(const u16x8*)&Hbf[(b * Tn + s0 + r) * Dn + c];
        *(u16x8*)((char*)Ks + (((r * 256 + c) * 2) ^ ((r & 7) << 4))) = v;
      }
    }
    {
      const int s = tid & 63, db = tid >> 6;
      #pragma unroll
      for (int jj = 0; jj < 8; ++jj){
        const int d0 = db * 64 + jj * 8;
        u16x8 v = *(const u16x8*)&Hbf[(b * Tn + s0 + s) * Dn + d0];
        #pragma unroll
        for (int e = 0; e < 8; ++e){
          const int d = d0 + e;
          *(unsigned short*)((char*)Vt + (((d * 64 + s) * 2) ^ ((d & 7) << 4))) = (unsigned short)v[e];
        }
      }
    }
    __syncthreads();
    f32x4 sacc[4];
    #pragma unroll
    for (int n = 0; n < 4; ++n) sacc[n] = (f32x4){0.f, 0.f, 0.f, 0.f};
    #pragma unroll
    for (int kc = 0; kc < 8; ++kc){
      #pragma unroll
      for (int n = 0; n < 4; ++n){
        const int r = n * 16 + lr, c = kc * 32 + lg * 8;
        bf16x8 kfr = *(const bf16x8*)((const char*)Ks + (((r * 256 + c) * 2) ^ ((r & 7) << 4)));
        sacc[n] = __builtin_amdgcn_mfma_f32_16x16x32_bf16(qf[kc], kfr, sacc[n], 0, 0, 0);
      }
    }
    if (kt == qt){
      #pragma unroll
      for (int n = 0; n < 4; ++n)
        #pragma unroll
        for (int i = 0; i < 4; ++i){
          const int scol = s0 + n * 16 + lr;
          const int qrow = q0 + w * 16 + lg * 4 + i;
          if (scol > qrow) sacc[n][i] = -__builtin_inff();
        }
    }
    float rmax[4], alpha[4], rsum[4];
    #pragma unroll
    for (int i = 0; i < 4; ++i){
      float vv = fmaxf(fmaxf(sacc[0][i], sacc[1][i]), fmaxf(sacc[2][i], sacc[3][i]));
      vv = fmaxf(vv, __shfl_xor(vv, 1));
      vv = fmaxf(vv, __shfl_xor(vv, 2));
      vv = fmaxf(vv, __shfl_xor(vv, 4));
      vv = fmaxf(vv, __shfl_xor(vv, 8));
      rmax[i] = vv;
    }
    #pragma unroll
    for (int i = 0; i < 4; ++i){
      const float mn = fmaxf(m_i[i], rmax[i]);
      alpha[i] = __expf(m_i[i] - mn);
      m_i[i] = mn;
      rsum[i] = 0.f;
    }
    #pragma unroll
    for (int n = 0; n < 4; ++n){
      #pragma unroll
      for (int i = 0; i < 4; ++i){
        const float pv = __expf(sacc[n][i] - m_i[i]);
        rsum[i] += pv;
        const int r = w * 16 + lg * 4 + i, c = n * 16 + lr;
        *(unsigned short*)((char*)Ps + (((r * 64 + c) * 2) ^ ((r & 7) << 4))) = f2bf(pv);
      }
    }
    #pragma unroll
    for (int i = 0; i < 4; ++i){
      float vv = rsum[i];
      vv += __shfl_xor(vv, 1);
      vv += __shfl_xor(vv, 2);
      vv += __shfl_xor(vv, 4);
      vv += __shfl_xor(vv, 8);
      l_i[i] = l_i[i] * alpha[i] + vv;
    }
    #pragma unroll
    for (int n = 0; n < 16; ++n)
      #pragma unroll
      for (int i = 0; i < 4; ++i) o_acc[n][i] *= alpha[i];
    #pragma unroll
    for (int kc = 0; kc < 2; ++kc){
      const int r = w * 16 + lr, c = kc * 32 + lg * 8;
      bf16x8 pfr = *(const bf16x8*)((const char*)Ps + (((r * 64 + c) * 2) ^ ((r & 7) << 4)));
      #pragma unroll
      for (int n = 0; n < 16; ++n){
        const int vr = n * 16 + lr, vc = kc * 32 + lg * 8;
        bf16x8 vfr = *(const bf16x8*)((const char*)Vt + (((vr * 64 + vc) * 2) ^ ((vr & 7) << 4)));
        o_acc[n] = __builtin_amdgcn_mfma_f32_16x16x32_bf16(pfr, vfr, o_acc[n], 0, 0, 0);
      }
    }
  }
  #pragma unroll
  for (int n = 0; n < 16; ++n)
    #pragma unroll
    for (int i = 0; i < 4; ++i){
      const float vv = o_acc[n][i] / l_i[i];
      const int q = q0 + w * 16 + lg * 4 + i;
      const int d = n * 16 + lr;
      ctxbf[(b * Tn + q) * Dn + d] = f2bf(vv);
    }
}

// ---------------------------------------------------------------------------
// MLP: out = relu([H|ctx] @ W1^T + b1) @ W2^T + b2, fused per 64-row M tile.
// ---------------------------------------------------------------------------
__global__ __launch_bounds__(256, 1) void mlp_kernel(
    const unsigned short* __restrict__ Hbf, const unsigned short* __restrict__ ctxbf,
    const float* __restrict__ W1, const float* __restrict__ b1,
    const float* __restrict__ W2, const float* __restrict__ b2,
    float* __restrict__ out)
{
  const int m0 = blockIdx.x * 64;
  const int tid = threadIdx.x;
  const int w = tid >> 6, l = tid & 63;
  const int lr = l & 15, lg = l >> 4;

  __shared__ unsigned short As[64 * 512];
  __shared__ unsigned short Ws[64 * 512];

  {
    const int r = tid >> 2, cs = (tid & 3) * 128;
    #pragma unroll
    for (int jj = 0; jj < 16; ++jj){
      const int c = cs + jj * 8;
      u16x8 v;
      if (c < 256) v = *(const u16x8*)&Hbf[(m0 + r) * Dn + c];
      else         v = *(const u16x8*)&ctxbf[(m0 + r) * Dn + (c - 256)];
      *(u16x8*)((char*)As + (((r * 512 + c) * 2) ^ ((r & 7) << 4))) = v;
    }
  }
  f32x4 hacc[16];
  #pragma unroll
  for (int n = 0; n < 16; ++n) hacc[n] = (f32x4){0.f, 0.f, 0.f, 0.f};

  for (int nb = 0; nb < 4; ++nb){
    __syncthreads();
    {
      const int r = tid >> 2, cs = (tid & 3) * 128;
      #pragma unroll
      for (int jj = 0; jj < 32; ++jj){
        const int c = cs + jj * 4;
        const float4 v = *(const float4*)&W1[(nb * 64 + r) * 512 + c];
        u16x4 pk = { f2bf(v.x), f2bf(v.y), f2bf(v.z), f2bf(v.w) };
        *(u16x4*)((char*)Ws + (((r * 512 + c) * 2) ^ ((r & 7) << 4))) = pk;
      }
    }
    __syncthreads();
    #pragma unroll
    for (int kc = 0; kc < 16; ++kc){
      const int ar = w * 16 + lr, ac = kc * 32 + lg * 8;
      bf16x8 af = *(const bf16x8*)((const char*)As + (((ar * 512 + ac) * 2) ^ ((ar & 7) << 4)));
      #pragma unroll
      for (int n = 0; n < 4; ++n){
        const int br = n * 16 + lr;
        bf16x8 bf = *(const bf16x8*)((const char*)Ws + (((br * 512 + ac) * 2) ^ ((br & 7) << 4)));
        hacc[nb * 4 + n] = __builtin_amdgcn_mfma_f32_16x16x32_bf16(af, bf, hacc[nb * 4 + n], 0, 0, 0);
      }
    }
  }
  __syncthreads();
  #pragma unroll
  for (int nn = 0; nn < 16; ++nn){
    const int col = (nn >> 2) * 64 + (nn & 3) * 16 + lr;
    const float bv = b1[col];
    #pragma unroll
    for (int i = 0; i < 4; ++i){
      float v = hacc[nn][i] + bv;
      v = v > 0.f ? v : 0.f;
      const int r = w * 16 + lg * 4 + i;
      *(unsigned short*)((char*)As + (((r * 256 + col) * 2) ^ ((r & 7) << 4))) = f2bf(v);
    }
  }
  {
    const int r = tid >> 2, cs = (tid & 3) * 64;
    #pragma unroll
    for (int jj = 0; jj < 16; ++jj){
      const int c = cs + jj * 4;
      const float4 v = *(const float4*)&W2[r * 256 + c];
      u16x4 pk = { f2bf(v.x), f2bf(v.y), f2bf(v.z), f2bf(v.w) };
      *(u16x4*)((char*)Ws + (((r * 256 + c) * 2) ^ ((r & 7) << 4))) = pk;
    }
  }
  __syncthreads();
  f32x4 oacc[4];
  #pragma unroll
  for (int n = 0; n < 4; ++n) oacc[n] = (f32x4){0.f, 0.f, 0.f, 0.f};
  #pragma unroll
  for (int kc = 0; kc < 8; ++kc){
    const int ar = w * 16 + lr, ac = kc * 32 + lg * 8;
    bf16x8 af = *(const bf16x8*)((const char*)As + (((ar * 256 + ac) * 2) ^ ((ar & 7) << 4)));
    #pragma unroll
    for (int n = 0; n < 4; ++n){
      const int br = n * 16 + lr;
      bf16x8 bf = *(const bf16x8*)((const char*)Ws + (((br * 256 + ac) * 2) ^ ((br & 7) << 4)));
      oacc[n] = __builtin_amdgcn_mfma_f32_16x16x32_bf16(af, bf, oacc[n], 0, 0, 0);
    }
  }
  #pragma unroll
  for (int n = 0; n < 4; ++n)
    #pragma unroll
    for (int i = 0; i < 4; ++i){
      const int ii = n * 16 + lr;
      const int m = m0 + w * 16 + lg * 4 + i;
      out[m * In + ii] = oacc[n][i] + b2[ii];
    }
}

extern "C" void kernel_launch(void* const* d_in, const int* in_sizes, int n_in,
                              void* d_out, int out_size, void* d_ws, size_t ws_size,
                              hipStream_t stream)
{
  (void)in_sizes; (void)n_in; (void)out_size; (void)ws_size;
  const float* x   = (const float*)d_in[0];
  const float* Wih = (const float*)d_in[1];
  const float* Whh = (const float*)d_in[2];
  const float* bih = (const float*)d_in[3];
  const float* bhh = (const float*)d_in[4];
  const float* W1  = (const float*)d_in[5];
  const float* b1  = (const float*)d_in[6];
  const float* W2  = (const float*)d_in[7];
  const float* b2  = (const float*)d_in[8];
  float* out = (float*)d_out;

  char* ws = (char*)d_ws;
  unsigned short* Hbf   = (unsigned short*)ws;                              // [0, 32M)
  unsigned short* ctxbf = (unsigned short*)(ws + (size_t)32 * 1024 * 1024); // [32M, 64M) attn out
  unsigned short* Gx    = (unsigned short*)(ws + (size_t)32 * 1024 * 1024); // [32M, 160M);
  // Gx is fully consumed by the scan BEFORE attn writes ctx over its head.

  gates_x_kernel<<<1024, 256, 0, stream>>>(x, Wih, bih, bhh, Gx);
  lstm_scan_kernel<<<4, 512, 0, stream>>>(Gx, Whh, Hbf);
  attn_kernel<<<Bn * 16, 256, 0, stream>>>(Hbf, ctxbf);
  mlp_kernel<<<(Bn * Tn) / 64, 256, 0, stream>>>(Hbf, ctxbf, W1, b1, W2, b2, out);
}

// Round 8
// 4144.387 us; speedup vs baseline: 1.3724x; 1.2160x over previous
//
#include <hip/hip_runtime.h>
#include <hip/hip_bf16.h>

#define Bn 64
#define Tn 1024
#define In 64
#define Dn 256

typedef short bf16x8 __attribute__((ext_vector_type(8)));
typedef unsigned short u16x8 __attribute__((ext_vector_type(8)));
typedef unsigned short u16x4 __attribute__((ext_vector_type(4)));
typedef float f32x4 __attribute__((ext_vector_type(4)));
typedef unsigned int u32x2 __attribute__((ext_vector_type(2)));

__device__ __forceinline__ unsigned short f2bf(float f){
  unsigned u = __float_as_uint(f);
  u += 0x7fffu + ((u >> 16) & 1u);       // RNE
  return (unsigned short)(u >> 16);
}
__device__ __forceinline__ float sig_(float x){ return 1.f / (1.f + __expf(-x)); }
__device__ __forceinline__ float tanh_(float x){ float e = __expf(2.f * x); return 1.f - 2.f / (e + 1.f); }

__device__ __forceinline__ bf16x8 pack8(const float* f){
  bf16x8 r;
  #pragma unroll
  for (int i = 0; i < 8; ++i) r[i] = (short)f2bf(f[i]);
  return r;
}

// ---------------------------------------------------------------------------
// gates_x: Gx = x @ Wih^T + bih + bhh, written bf16 in the scan's fragment
// layout: per (chain,t,u): [jmt 8][lane 64][gate 4]. Lane (lg,lr) of slot
// (u,j,mt) holds gates i=0..3 of dim = u*32+j*16+lg*4+mt, batch = chain*16+lr.
// ---------------------------------------------------------------------------
__global__ __launch_bounds__(256, 1) void gates_x_kernel(
    const float* __restrict__ x, const float* __restrict__ Wih,
    const float* __restrict__ bih, const float* __restrict__ bhh,
    unsigned short* __restrict__ Gx)
{
  const int bid = blockIdx.x;
  const int chain = bid >> 8;
  const int t0 = (bid & 255) * 4;
  const int tid = threadIdx.x;
  const int wv = tid >> 6;
  const int l = tid & 63;
  const int lr = l & 15, lg = l >> 4;
  const int gate = lr & 3, dimx = lr >> 2;

  __shared__ float bsum[1024];
  for (int r = tid; r < 1024; r += 256) bsum[r] = bih[r] + bhh[r];
  __syncthreads();

  bf16x8 wa[16][2];
  #pragma unroll
  for (int up = 0; up < 2; ++up)
    #pragma unroll
    for (int j = 0; j < 2; ++j)
      #pragma unroll
      for (int mt = 0; mt < 4; ++mt){
        const int u = wv * 2 + up;
        const int row = gate * Dn + u * 32 + j * 16 + dimx * 4 + mt;
        #pragma unroll
        for (int kt = 0; kt < 2; ++kt){
          float tmp[8];
          *(float4*)&tmp[0] = *(const float4*)&Wih[row * In + kt * 32 + lg * 8];
          *(float4*)&tmp[4] = *(const float4*)&Wih[row * In + kt * 32 + lg * 8 + 4];
          wa[(up * 2 + j) * 4 + mt][kt] = pack8(tmp);
        }
      }

  const int b = chain * 16 + lr;
  for (int tt = 0; tt < 4; ++tt){
    const int t = t0 + tt;
    bf16x8 xb[2];
    #pragma unroll
    for (int kt = 0; kt < 2; ++kt){
      float tmp[8];
      *(float4*)&tmp[0] = *(const float4*)&x[(size_t)(b * Tn + t) * In + kt * 32 + lg * 8];
      *(float4*)&tmp[4] = *(const float4*)&x[(size_t)(b * Tn + t) * In + kt * 32 + lg * 8 + 4];
      xb[kt] = pack8(tmp);
    }
    #pragma unroll
    for (int up = 0; up < 2; ++up)
      #pragma unroll
      for (int j = 0; j < 2; ++j)
        #pragma unroll
        for (int mt = 0; mt < 4; ++mt){
          const int u = wv * 2 + up;
          f32x4 a = {0.f, 0.f, 0.f, 0.f};
          a = __builtin_amdgcn_mfma_f32_16x16x32_bf16(wa[(up*2+j)*4+mt][0], xb[0], a, 0, 0, 0);
          a = __builtin_amdgcn_mfma_f32_16x16x32_bf16(wa[(up*2+j)*4+mt][1], xb[1], a, 0, 0, 0);
          const int dim = u * 32 + j * 16 + lg * 4 + mt;
          u16x4 o;
          #pragma unroll
          for (int i = 0; i < 4; ++i) o[i] = f2bf(a[i] + bsum[i * Dn + dim]);
          const size_t off = (((size_t)(chain * Tn + t) * 8 + u) * 8 + (j * 4 + mt)) * 256
                             + (lg * 16 + lr) * 4;
          *(u16x4*)&Gx[off] = o;
        }
  }
}

// ---------------------------------------------------------------------------
// LSTM scan v8: 4 WGs (one per 16-batch chain) x 512 threads (8 waves), all
// on one CU each — zero inter-CU communication. Wave u owns dims
// [u*32,u*32+32) x 4 gates; K=256 (x-path precomputed in Gx).
// Register-demand-reduced vs v7 (the v7 allocator fell to a 128-reg split
// and spilled the weight array to scratch — 4.3us/step was weight reload):
//  - two-pass acc (j=0 tiles then j=1 tiles): 16 acc regs live, not 32
//  - hL double-buffered (parity) -> EW writes p^1 while reads hit p: ONE
//    barrier per step, no WAR hazard
//  - Gx loads split: gA before pass A, gB after EW-A frees gA (8 live regs)
//  - waves_per_eu(2,2): pin the 256-VGPR/wave budget
// Weights: 46 frag-units in regs (184 VGPR), 18 in LDS (144 KB).
// LDS = 147456 + 16384 = 163840 B (exact 160 KiB fit).
// ---------------------------------------------------------------------------
__global__ void __attribute__((amdgpu_flat_work_group_size(512, 512),
                               amdgpu_waves_per_eu(2, 2)))
lstm_scan_kernel(
    const unsigned short* __restrict__ Gx, const float* __restrict__ Whh,
    unsigned short* __restrict__ Hbf)
{
  const int chain = blockIdx.x;
  const int tid = threadIdx.x;
  const int u = tid >> 6;
  const int l = tid & 63;
  const int lr = l & 15, lg = l >> 4;
  const int gate = lr & 3, dimx = lr >> 2;

  __shared__ unsigned short WL[8][18 * 512];     // 144 KB
  __shared__ unsigned short hL[2][32][16][8];    // 16 KB (double-buffered)

  // ---- register weight fragments (46 units = 184 VGPR) ----
  bf16x8 w0[4][8], w1m0[8], w1m3h[6];
  #pragma unroll
  for (int mt = 0; mt < 4; ++mt){
    const int row = gate * Dn + u * 32 + dimx * 4 + mt;          // j=0
    #pragma unroll
    for (int kt = 0; kt < 8; ++kt){
      float tmp[8];
      *(float4*)&tmp[0] = *(const float4*)&Whh[row * Dn + kt * 32 + lg * 8];
      *(float4*)&tmp[4] = *(const float4*)&Whh[row * Dn + kt * 32 + lg * 8 + 4];
      w0[mt][kt] = pack8(tmp);
    }
  }
  {
    const int row = gate * Dn + u * 32 + 16 + dimx * 4 + 0;      // j=1, mt=0
    #pragma unroll
    for (int kt = 0; kt < 8; ++kt){
      float tmp[8];
      *(float4*)&tmp[0] = *(const float4*)&Whh[row * Dn + kt * 32 + lg * 8];
      *(float4*)&tmp[4] = *(const float4*)&Whh[row * Dn + kt * 32 + lg * 8 + 4];
      w1m0[kt] = pack8(tmp);
    }
  }
  {
    const int row = gate * Dn + u * 32 + 16 + dimx * 4 + 3;      // j=1, mt=3, kt2..7
    #pragma unroll
    for (int kt = 2; kt < 8; ++kt){
      float tmp[8];
      *(float4*)&tmp[0] = *(const float4*)&Whh[row * Dn + kt * 32 + lg * 8];
      *(float4*)&tmp[4] = *(const float4*)&Whh[row * Dn + kt * 32 + lg * 8 + 4];
      w1m3h[kt - 2] = pack8(tmp);
    }
  }
  // ---- LDS weight staging (18 units/wave = 18 KB/wave) ----
  // units 0..7 = (j1,mt1,kt), 8..15 = (j1,mt2,kt), 16..17 = (j1,mt3,kt0..1)
  #pragma unroll
  for (int mt = 1; mt < 3; ++mt){
    const int row = gate * Dn + u * 32 + 16 + dimx * 4 + mt;
    #pragma unroll
    for (int kt = 0; kt < 8; ++kt){
      float tmp[8];
      *(float4*)&tmp[0] = *(const float4*)&Whh[row * Dn + kt * 32 + lg * 8];
      *(float4*)&tmp[4] = *(const float4*)&Whh[row * Dn + kt * 32 + lg * 8 + 4];
      *(bf16x8*)&WL[u][((mt - 1) * 8 + kt) * 512 + lg * 128 + lr * 8] = pack8(tmp);
    }
  }
  {
    const int row = gate * Dn + u * 32 + 16 + dimx * 4 + 3;
    #pragma unroll
    for (int kt = 0; kt < 2; ++kt){
      float tmp[8];
      *(float4*)&tmp[0] = *(const float4*)&Whh[row * Dn + kt * 32 + lg * 8];
      *(float4*)&tmp[4] = *(const float4*)&Whh[row * Dn + kt * 32 + lg * 8 + 4];
      *(bf16x8*)&WL[u][(16 + kt) * 512 + lg * 128 + lr * 8] = pack8(tmp);
    }
  }
  // zero both hL parities (h(-1) = 0)
  for (int i = tid; i < 2 * 32 * 16 * 8; i += 512) ((unsigned short*)hL)[i] = 0;
  __syncthreads();

  float cst[8] = {0.f, 0.f, 0.f, 0.f, 0.f, 0.f, 0.f, 0.f};
  const int lane64 = lg * 16 + lr;
  const size_t hbB = (size_t)(chain * 16 + lr) * Tn * Dn;
  const int db0 = u * 4 + (lg >> 1);
  const int hoff = (lg & 1) * 4;

  for (int t = 0; t < Tn; ++t){
    const int p = t & 1;
    const unsigned short* gxp = Gx + ((size_t)(chain * Tn + t) * 8 + u) * 2048;

    // Gx first half (jm 0..3)
    u32x2 gA[4];
    #pragma unroll
    for (int jm = 0; jm < 4; ++jm)
      gA[jm] = *(const u32x2*)&gxp[jm * 256 + lane64 * 4];

    // ---- pass A: j=0 tiles, register weights only ----
    f32x4 acc[4];
    #pragma unroll
    for (int i = 0; i < 4; ++i) acc[i] = (f32x4){0.f, 0.f, 0.f, 0.f};
    #pragma unroll
    for (int kt = 0; kt < 8; ++kt){
      const bf16x8 hf = *(const bf16x8*)&hL[p][kt * 4 + lg][lr][0];
      acc[0] = __builtin_amdgcn_mfma_f32_16x16x32_bf16(w0[0][kt], hf, acc[0], 0, 0, 0);
      acc[1] = __builtin_amdgcn_mfma_f32_16x16x32_bf16(w0[1][kt], hf, acc[1], 0, 0, 0);
      acc[2] = __builtin_amdgcn_mfma_f32_16x16x32_bf16(w0[2][kt], hf, acc[2], 0, 0, 0);
      acc[3] = __builtin_amdgcn_mfma_f32_16x16x32_bf16(w0[3][kt], hf, acc[3], 0, 0, 0);
    }
    // ---- EW-A: dims u*32 + lg*4 + mt ----
    {
      unsigned long long hq0 = 0;
      #pragma unroll
      for (int mt = 0; mt < 4; ++mt){
        const unsigned glo = gA[mt][0], ghi = gA[mt][1];
        const float gi = __uint_as_float(glo << 16)         + acc[mt][0];
        const float gf = __uint_as_float(glo & 0xFFFF0000u) + acc[mt][1];
        const float gg = __uint_as_float(ghi << 16)         + acc[mt][2];
        const float go = __uint_as_float(ghi & 0xFFFF0000u) + acc[mt][3];
        const float ig = sig_(gi), fg = sig_(gf), gv = tanh_(gg), og = sig_(go);
        const float c = fg * cst[mt] + ig * gv;
        cst[mt] = c;
        const float h = og * tanh_(c);
        hq0 |= (unsigned long long)f2bf(h) << (16 * mt);
      }
      *(unsigned long long*)&hL[p ^ 1][db0][lr][hoff] = hq0;      // j=0 dims
      *(unsigned long long*)&Hbf[hbB + (size_t)t * Dn + u * 32 + lg * 4] = hq0;
    }

    // Gx second half (jm 4..7) — gA regs are dead now
    u32x2 gB[4];
    #pragma unroll
    for (int jm = 0; jm < 4; ++jm)
      gB[jm] = *(const u32x2*)&gxp[(4 + jm) * 256 + lane64 * 4];

    // ---- pass B: j=1 tiles, LDS-heavy weights ----
    #pragma unroll
    for (int i = 0; i < 4; ++i) acc[i] = (f32x4){0.f, 0.f, 0.f, 0.f};
    #pragma unroll
    for (int kt = 0; kt < 8; ++kt){
      const bf16x8 hf = *(const bf16x8*)&hL[p][kt * 4 + lg][lr][0];
      acc[0] = __builtin_amdgcn_mfma_f32_16x16x32_bf16(w1m0[kt], hf, acc[0], 0, 0, 0);
      acc[1] = __builtin_amdgcn_mfma_f32_16x16x32_bf16(
                 *(const bf16x8*)&WL[u][(0 * 8 + kt) * 512 + lg * 128 + lr * 8], hf, acc[1], 0, 0, 0);
      acc[2] = __builtin_amdgcn_mfma_f32_16x16x32_bf16(
                 *(const bf16x8*)&WL[u][(1 * 8 + kt) * 512 + lg * 128 + lr * 8], hf, acc[2], 0, 0, 0);
      bf16x8 a7;
      if (kt < 2) a7 = *(const bf16x8*)&WL[u][(16 + kt) * 512 + lg * 128 + lr * 8];
      else        a7 = w1m3h[kt - 2];
      acc[3] = __builtin_amdgcn_mfma_f32_16x16x32_bf16(a7, hf, acc[3], 0, 0, 0);
    }
    // ---- EW-B: dims u*32 + 16 + lg*4 + mt ----
    {
      unsigned long long hq1 = 0;
      #pragma unroll
      for (int mt = 0; mt < 4; ++mt){
        const unsigned glo = gB[mt][0], ghi = gB[mt][1];
        const float gi = __uint_as_float(glo << 16)         + acc[mt][0];
        const float gf = __uint_as_float(glo & 0xFFFF0000u) + acc[mt][1];
        const float gg = __uint_as_float(ghi << 16)         + acc[mt][2];
        const float go = __uint_as_float(ghi & 0xFFFF0000u) + acc[mt][3];
        const float ig = sig_(gi), fg = sig_(gf), gv = tanh_(gg), og = sig_(go);
        const float c = fg * cst[4 + mt] + ig * gv;
        cst[4 + mt] = c;
        const float h = og * tanh_(c);
        hq1 |= (unsigned long long)f2bf(h) << (16 * mt);
      }
      *(unsigned long long*)&hL[p ^ 1][db0 + 2][lr][hoff] = hq1;  // j=1 dims
      *(unsigned long long*)&Hbf[hbB + (size_t)t * Dn + u * 32 + 16 + lg * 4] = hq1;
    }
    __syncthreads();   // hL[p^1] complete; all hL[p] readers done -> next step
  }
}

// ---------------------------------------------------------------------------
// Flash attention, Q=K=V=H (bf16), unscaled, causal. One WG per (b, 64-row qtile).
// ---------------------------------------------------------------------------
__global__ __launch_bounds__(256, 1) void attn_kernel(
    const unsigned short* __restrict__ Hbf, unsigned short* __restrict__ ctxbf)
{
  const int bid = blockIdx.x;
  const int b = bid >> 4, qt = bid & 15;
  const int q0 = qt * 64;
  const int tid = threadIdx.x;
  const int w = tid >> 6, l = tid & 63;
  const int lr = l & 15, lg = l >> 4;

  __shared__ unsigned short Qs[64 * 256];
  __shared__ unsigned short Ks[64 * 256];
  __shared__ unsigned short Vt[256 * 64];   // transposed: [d][s]
  __shared__ unsigned short Ps[64 * 64];

  {
    const int r = tid >> 2, cs = (tid & 3) * 64;
    #pragma unroll
    for (int jj = 0; jj < 8; ++jj){
      const int c = cs + jj * 8;
      u16x8 v = *(const u16x8*)&Hbf[(b * Tn + q0 + r) * Dn + c];
      *(u16x8*)((char*)Qs + (((r * 256 + c) * 2) ^ ((r & 7) << 4))) = v;
    }
  }
  __syncthreads();
  bf16x8 qf[8];
  #pragma unroll
  for (int kc = 0; kc < 8; ++kc){
    const int r = w * 16 + lr, c = kc * 32 + lg * 8;
    qf[kc] = *(const bf16x8*)((const char*)Qs + (((r * 256 + c) * 2) ^ ((r & 7) << 4)));
  }

  float m_i[4], l_i[4];
  f32x4 o_acc[16];
  #pragma unroll
  for (int i = 0; i < 4; ++i){ m_i[i] = -__builtin_inff(); l_i[i] = 0.f; }
  #pragma unroll
  for (int n = 0; n < 16; ++n) o_acc[n] = (f32x4){0.f, 0.f, 0.f, 0.f};

  for (int kt = 0; kt <= qt; ++kt){
    const int s0 = kt * 64;
    __syncthreads();
    {
      const int r = tid >> 2, cs = (tid & 3) * 64;
      #pragma unroll
      for (int jj = 0; jj < 8; ++jj){
        const int c = cs + jj * 8;
        u16x8 v = *(const u16x8*)&Hbf[(b * Tn + s0 + r) * Dn + c];
        *(u16x8*)((char*)Ks + (((r * 256 + c) * 2) ^ ((r & 7) << 4))) = v;
      }
    }
    {
      const int s = tid & 63, db = tid >> 6;
      #pragma unroll
      for (int jj = 0; jj < 8; ++jj){
        const int d0 = db * 64 + jj * 8;
        u16x8 v = *(const u16x8*)&Hbf[(b * Tn + s0 + s) * Dn + d0];
        #pragma unroll
        for (int e = 0; e < 8; ++e){
          const int d = d0 + e;
          *(unsigned short*)((char*)Vt + (((d * 64 + s) * 2) ^ ((d & 7) << 4))) = (unsigned short)v[e];
        }
      }
    }
    __syncthreads();
    f32x4 sacc[4];
    #pragma unroll
    for (int n = 0; n < 4; ++n) sacc[n] = (f32x4){0.f, 0.f, 0.f, 0.f};
    #pragma unroll
    for (int kc = 0; kc < 8; ++kc){
      #pragma unroll
      for (int n = 0; n < 4; ++n){
        const int r = n * 16 + lr, c = kc * 32 + lg * 8;
        bf16x8 kfr = *(const bf16x8*)((const char*)Ks + (((r * 256 + c) * 2) ^ ((r & 7) << 4)));
        sacc[n] = __builtin_amdgcn_mfma_f32_16x16x32_bf16(qf[kc], kfr, sacc[n], 0, 0, 0);
      }
    }
    if (kt == qt){
      #pragma unroll
      for (int n = 0; n < 4; ++n)
        #pragma unroll
        for (int i = 0; i < 4; ++i){
          const int scol = s0 + n * 16 + lr;
          const int qrow = q0 + w * 16 + lg * 4 + i;
          if (scol > qrow) sacc[n][i] = -__builtin_inff();
        }
    }
    float rmax[4], alpha[4], rsum[4];
    #pragma unroll
    for (int i = 0; i < 4; ++i){
      float vv = fmaxf(fmaxf(sacc[0][i], sacc[1][i]), fmaxf(sacc[2][i], sacc[3][i]));
      vv = fmaxf(vv, __shfl_xor(vv, 1));
      vv = fmaxf(vv, __shfl_xor(vv, 2));
      vv = fmaxf(vv, __shfl_xor(vv, 4));
      vv = fmaxf(vv, __shfl_xor(vv, 8));
      rmax[i] = vv;
    }
    #pragma unroll
    for (int i = 0; i < 4; ++i){
      const float mn = fmaxf(m_i[i], rmax[i]);
      alpha[i] = __expf(m_i[i] - mn);
      m_i[i] = mn;
      rsum[i] = 0.f;
    }
    #pragma unroll
    for (int n = 0; n < 4; ++n){
      #pragma unroll
      for (int i = 0; i < 4; ++i){
        const float pv = __expf(sacc[n][i] - m_i[i]);
        rsum[i] += pv;
        const int r = w * 16 + lg * 4 + i, c = n * 16 + lr;
        *(unsigned short*)((char*)Ps + (((r * 64 + c) * 2) ^ ((r & 7) << 4))) = f2bf(pv);
      }
    }
    #pragma unroll
    for (int i = 0; i < 4; ++i){
      float vv = rsum[i];
      vv += __shfl_xor(vv, 1);
      vv += __shfl_xor(vv, 2);
      vv += __shfl_xor(vv, 4);
      vv += __shfl_xor(vv, 8);
      l_i[i] = l_i[i] * alpha[i] + vv;
    }
    #pragma unroll
    for (int n = 0; n < 16; ++n)
      #pragma unroll
      for (int i = 0; i < 4; ++i) o_acc[n][i] *= alpha[i];
    #pragma unroll
    for (int kc = 0; kc < 2; ++kc){
      const int r = w * 16 + lr, c = kc * 32 + lg * 8;
      bf16x8 pfr = *(const bf16x8*)((const char*)Ps + (((r * 64 + c) * 2) ^ ((r & 7) << 4)));
      #pragma unroll
      for (int n = 0; n < 16; ++n){
        const int vr = n * 16 + lr, vc = kc * 32 + lg * 8;
        bf16x8 vfr = *(const bf16x8*)((const char*)Vt + (((vr * 64 + vc) * 2) ^ ((vr & 7) << 4)));
        o_acc[n] = __builtin_amdgcn_mfma_f32_16x16x32_bf16(pfr, vfr, o_acc[n], 0, 0, 0);
      }
    }
  }
  #pragma unroll
  for (int n = 0; n < 16; ++n)
    #pragma unroll
    for (int i = 0; i < 4; ++i){
      const float vv = o_acc[n][i] / l_i[i];
      const int q = q0 + w * 16 + lg * 4 + i;
      const int d = n * 16 + lr;
      ctxbf[(b * Tn + q) * Dn + d] = f2bf(vv);
    }
}

// ---------------------------------------------------------------------------
// MLP: out = relu([H|ctx] @ W1^T + b1) @ W2^T + b2, fused per 64-row M tile.
// ---------------------------------------------------------------------------
__global__ __launch_bounds__(256, 1) void mlp_kernel(
    const unsigned short* __restrict__ Hbf, const unsigned short* __restrict__ ctxbf,
    const float* __restrict__ W1, const float* __restrict__ b1,
    const float* __restrict__ W2, const float* __restrict__ b2,
    float* __restrict__ out)
{
  const int m0 = blockIdx.x * 64;
  const int tid = threadIdx.x;
  const int w = tid >> 6, l = tid & 63;
  const int lr = l & 15, lg = l >> 4;

  __shared__ unsigned short As[64 * 512];
  __shared__ unsigned short Ws[64 * 512];

  {
    const int r = tid >> 2, cs = (tid & 3) * 128;
    #pragma unroll
    for (int jj = 0; jj < 16; ++jj){
      const int c = cs + jj * 8;
      u16x8 v;
      if (c < 256) v = *(const u16x8*)&Hbf[(m0 + r) * Dn + c];
      else         v = *(const u16x8*)&ctxbf[(m0 + r) * Dn + (c - 256)];
      *(u16x8*)((char*)As + (((r * 512 + c) * 2) ^ ((r & 7) << 4))) = v;
    }
  }
  f32x4 hacc[16];
  #pragma unroll
  for (int n = 0; n < 16; ++n) hacc[n] = (f32x4){0.f, 0.f, 0.f, 0.f};

  for (int nb = 0; nb < 4; ++nb){
    __syncthreads();
    {
      const int r = tid >> 2, cs = (tid & 3) * 128;
      #pragma unroll
      for (int jj = 0; jj < 32; ++jj){
        const int c = cs + jj * 4;
        const float4 v = *(const float4*)&W1[(nb * 64 + r) * 512 + c];
        u16x4 pk = { f2bf(v.x), f2bf(v.y), f2bf(v.z), f2bf(v.w) };
        *(u16x4*)((char*)Ws + (((r * 512 + c) * 2) ^ ((r & 7) << 4))) = pk;
      }
    }
    __syncthreads();
    #pragma unroll
    for (int kc = 0; kc < 16; ++kc){
      const int ar = w * 16 + lr, ac = kc * 32 + lg * 8;
      bf16x8 af = *(const bf16x8*)((const char*)As + (((ar * 512 + ac) * 2) ^ ((ar & 7) << 4)));
      #pragma unroll
      for (int n = 0; n < 4; ++n){
        const int br = n * 16 + lr;
        bf16x8 bf = *(const bf16x8*)((const char*)Ws + (((br * 512 + ac) * 2) ^ ((br & 7) << 4)));
        hacc[nb * 4 + n] = __builtin_amdgcn_mfma_f32_16x16x32_bf16(af, bf, hacc[nb * 4 + n], 0, 0, 0);
      }
    }
  }
  __syncthreads();
  #pragma unroll
  for (int nn = 0; nn < 16; ++nn){
    const int col = (nn >> 2) * 64 + (nn & 3) * 16 + lr;
    const float bv = b1[col];
    #pragma unroll
    for (int i = 0; i < 4; ++i){
      float v = hacc[nn][i] + bv;
      v = v > 0.f ? v : 0.f;
      const int r = w * 16 + lg * 4 + i;
      *(unsigned short*)((char*)As + (((r * 256 + col) * 2) ^ ((r & 7) << 4))) = f2bf(v);
    }
  }
  {
    const int r = tid >> 2, cs = (tid & 3) * 64;
    #pragma unroll
    for (int jj = 0; jj < 16; ++jj){
      const int c = cs + jj * 4;
      const float4 v = *(const float4*)&W2[r * 256 + c];
      u16x4 pk = { f2bf(v.x), f2bf(v.y), f2bf(v.z), f2bf(v.w) };
      *(u16x4*)((char*)Ws + (((r * 256 + c) * 2) ^ ((r & 7) << 4))) = pk;
    }
  }
  __syncthreads();
  f32x4 oacc[4];
  #pragma unroll
  for (int n = 0; n < 4; ++n) oacc[n] = (f32x4){0.f, 0.f, 0.f, 0.f};
  #pragma unroll
  for (int kc = 0; kc < 8; ++kc){
    const int ar = w * 16 + lr, ac = kc * 32 + lg * 8;
    bf16x8 af = *(const bf16x8*)((const char*)As + (((ar * 256 + ac) * 2) ^ ((ar & 7) << 4)));
    #pragma unroll
    for (int n = 0; n < 4; ++n){
      const int br = n * 16 + lr;
      bf16x8 bf = *(const bf16x8*)((const char*)Ws + (((br * 256 + ac) * 2) ^ ((br & 7) << 4)));
      oacc[n] = __builtin_amdgcn_mfma_f32_16x16x32_bf16(af, bf, oacc[n], 0, 0, 0);
    }
  }
  #pragma unroll
  for (int n = 0; n < 4; ++n)
    #pragma unroll
    for (int i = 0; i < 4; ++i){
      const int ii = n * 16 + lr;
      const int m = m0 + w * 16 + lg * 4 + i;
      out[m * In + ii] = oacc[n][i] + b2[ii];
    }
}

extern "C" void kernel_launch(void* const* d_in, const int* in_sizes, int n_in,
                              void* d_out, int out_size, void* d_ws, size_t ws_size,
                              hipStream_t stream)
{
  (void)in_sizes; (void)n_in; (void)out_size; (void)ws_size;
  const float* x   = (const float*)d_in[0];
  const float* Wih = (const float*)d_in[1];
  const float* Whh = (const float*)d_in[2];
  const float* bih = (const float*)d_in[3];
  const float* bhh = (const float*)d_in[4];
  const float* W1  = (const float*)d_in[5];
  const float* b1  = (const float*)d_in[6];
  const float* W2  = (const float*)d_in[7];
  const float* b2  = (const float*)d_in[8];
  float* out = (float*)d_out;

  char* ws = (char*)d_ws;
  unsigned short* Hbf   = (unsigned short*)ws;                              // [0, 32M)
  unsigned short* ctxbf = (unsigned short*)(ws + (size_t)32 * 1024 * 1024); // [32M, 64M) attn out
  unsigned short* Gx    = (unsigned short*)(ws + (size_t)32 * 1024 * 1024); // [32M, 160M)
  // Gx is fully consumed by the scan BEFORE attn writes ctx over its head.

  gates_x_kernel<<<1024, 256, 0, stream>>>(x, Wih, bih, bhh, Gx);
  lstm_scan_kernel<<<4, 512, 0, stream>>>(Gx, Whh, Hbf);
  attn_kernel<<<Bn * 16, 256, 0, stream>>>(Hbf, ctxbf);
  mlp_kernel<<<(Bn * Tn) / 64, 256, 0, stream>>>(Hbf, ctxbf, W1, b1, W2, b2, out);
}